// Round 8
// baseline (97.701 us; speedup 1.0000x reference)
//
#include <hip/hip_runtime.h>
#include <hip/hip_bf16.h>
#include <math.h>

#define C_    128
#define NQ_   8
#define NK_   32768
#define QNK_  (NQ_*NK_)
#define NCH_  256         // softmax chunks of 128 cols

// ws float offsets
#define AQ_OFF     0        // [q][o] 1024
#define MINKEY_OFF 1024     // 1 uint (order-preserving float key)
#define DENOM_OFF  1040     // 8*256
#define OUTV_OFF   4096     // 256*1024 -> 266240
#define WSA_OFF    266240   // A-frag table: 64 frags x 64 lanes x 8 bf16 = 16384 u32
#define BH_OFF     282624   // Bk frag table: 256 kt x 4 ct x 4 w x 64 lanes x 8 u32 = 2M u32

typedef float f32x4  __attribute__((ext_vector_type(4)));
typedef float f32x16 __attribute__((ext_vector_type(16)));
typedef int   i32x4  __attribute__((ext_vector_type(4)));
typedef short bf16x8 __attribute__((ext_vector_type(8)));
typedef unsigned int u32x4 __attribute__((ext_vector_type(4)));

__device__ inline unsigned short f2bf(float f){ // prep only
  unsigned u = __float_as_uint(f);
  return (unsigned short)((u + 0x7FFFu + ((u >> 16) & 1u)) >> 16);
}
__device__ inline unsigned int pkbf(float a, float b){
  __hip_bfloat162 h = __float22bfloat162_rn(make_float2(a, b)); // v_cvt_pk_bf16_f32
  union { __hip_bfloat162 h2; unsigned int u; } cv; cv.h2 = h; return cv.u;
}
__device__ inline float bf_lo(unsigned u){ return __uint_as_float(u << 16); }
__device__ inline float bf_hi(unsigned u){ return __uint_as_float(u & 0xFFFF0000u); }
__device__ inline unsigned int fkey(float f){
  unsigned u = __float_as_uint(f);
  return (u & 0x80000000u) ? ~u : (u | 0x80000000u);
}
__device__ inline float fkey_dec(unsigned key){
  unsigned u = (key & 0x80000000u) ? (key & 0x7FFFFFFFu) : ~key;
  return __uint_as_float(u);
}

// ---------------- prep0: A-frag table (32x32x16 layout) + Aq + minkey init ----
// frag f = part*32 + ot*8 + ks; element [f][l][e] =
//   W1[ (ot*32 + (l&31))*384 + 128 + part*128 + ks*16 + (l>>5)*8 + e ]
__global__ __launch_bounds__(256) void prep_kernel(const float* __restrict__ query,
    const float* __restrict__ W1, const float* __restrict__ b1, float* __restrict__ ws){
  const int t = threadIdx.x, b = blockIdx.x;
  if (b < 16){
    unsigned int* wsa = (unsigned int*)(ws + WSA_OFF);
    for (int u = b*1024 + t; u < (b+1)*1024; u += 256){
      unsigned int pack = 0;
#pragma unroll
      for (int e2 = 0; e2 < 2; e2++){
        const int E = u*2 + e2;
        const int f = E >> 9, l = (E >> 3) & 63, e = E & 7;
        const int part = f >> 5, ot = (f >> 3) & 3, ks = f & 7;
        const int o = ot*32 + (l & 31);
        const int c = ks*16 + ((l >> 5) << 3) + e;
        pack |= (unsigned int)f2bf(W1[o*384 + 128 + part*128 + c]) << (16*e2);
      }
      wsa[u] = pack;
    }
  } else {
    if (t == 0) *(unsigned int*)(ws + MINKEY_OFF) = 0xFFFFFFFFu;
    const int o = t >> 1, h = t & 1;
    float s[8];
#pragma unroll
    for (int q = 0; q < 8; q++) s[q] = 0.f;
    for (int c = h*64; c < h*64 + 64; c++){
      const float wv = W1[o*384 + c];
#pragma unroll
      for (int q = 0; q < 8; q++) s[q] += wv * query[c*8 + q];
    }
#pragma unroll
    for (int q = 0; q < 8; q++){
      s[q] += __shfl_xor(s[q], 1, 64);
      if (h == 0) ws[AQ_OFF + q*128 + o] = s[q] + b1[o];
    }
  }
}

// ---- shared staging: fp32 [c][n]-global -> swizzled bf16 LDS [n 128][c 128] ----
// thread: h = 2w + (l>>5) (c-octet), n4 = (l&31)*4. b128 LDS writes.
// element (n, c): byte = n*256 + ( (c*2 within row) ^ (((n>>2)&7)<<4) )
__device__ inline void stage_tile(const float* __restrict__ src, size_t stride,
                                  unsigned short* __restrict__ lds, int w, int l){
  const int h  = 2*w + (l >> 5);
  const int n4 = (l & 31)*4;
  const float* base = src + (size_t)(h*8)*stride + n4;
#pragma unroll
  for (int p = 0; p < 2; p++){
    f32x4 v[8];
#pragma unroll
    for (int s = 0; s < 8; s++)
      v[s] = __builtin_nontemporal_load((const f32x4*)(base + (size_t)(64*p + s)*stride));
#pragma unroll
    for (int j = 0; j < 4; j++){
      const int n = n4 + j;
      u32x4 pk;
      pk[0] = pkbf(v[0][j], v[1][j]);
      pk[1] = pkbf(v[2][j], v[3][j]);
      pk[2] = pkbf(v[4][j], v[5][j]);
      pk[3] = pkbf(v[6][j], v[7][j]);
      const int byte = n*256 + ((h*16 + p*128) ^ (((n >> 2) & 7) << 4));
      *(u32x4*)((char*)lds + byte) = pk;
    }
  }
}

// ---------------- bkprep: BH[kt][ct][w][lane][16] = C-frags of W1k x keys -----
__global__ __launch_bounds__(256) void bkprep_kernel(const float* __restrict__ keys,
    float* __restrict__ ws){
  __shared__ unsigned short b_lds[128*128]; // 128n x 128c bf16 = 32KB
  const int t = threadIdx.x, w = t >> 6, l = t & 63;
  const int blk = blockIdx.x, k0 = blk*128;

  const bf16x8* wsa8 = (const bf16x8*)(ws + WSA_OFF);
  bf16x8 afr[8];
#pragma unroll
  for (int ks = 0; ks < 8; ks++) afr[ks] = wsa8[(w*8 + ks)*64 + l];   // part 0

  stage_tile(keys + k0, NK_, b_lds, w, l);
  __syncthreads();

  unsigned int* bh = (unsigned int*)(ws + BH_OFF);
  const int nn = l & 31;
  const int cb2 = ((l >> 5) << 3)*2;   // byte offset of this lane's c-octet
#pragma unroll
  for (int ct = 0; ct < 4; ct++){
    f32x16 acc = {};
    const int n = ct*32 + nn;
    const int swz = ((n >> 2) & 7) << 4;
#pragma unroll
    for (int ks = 0; ks < 8; ks++){
      const int byte = n*256 + ((ks*32 + cb2) ^ swz);     // FIXED: XOR full byte-in-row
      const bf16x8 bfr = *(const bf16x8*)((char*)b_lds + byte);
      acc = __builtin_amdgcn_mfma_f32_32x32x16_bf16(afr[ks], bfr, acc, 0, 0, 0);
    }
    u32x4 pA, pB;
#pragma unroll
    for (int j = 0; j < 4; j++){ pA[j] = pkbf(acc[2*j], acc[2*j+1]);
                                 pB[j] = pkbf(acc[8+2*j], acc[9+2*j]); }
    unsigned int* dst = bh + (size_t)(((blk*4 + ct)*4 + w)*64 + l)*8;
    *(u32x4*)dst = pA;
    *(u32x4*)(dst + 4) = pB;
  }
}

// ---------------- scores: one-shot 128-col blocks, 32x32x16 MFMA --------------
__global__ __launch_bounds__(256) void scores_kernel(
    const float* __restrict__ dist, const float* __restrict__ W2,
    const float* __restrict__ b2p, float* __restrict__ ws,
    float* __restrict__ scores)
{
  __shared__ unsigned short b_lds[128*128];   // 32KB swizzled [n][c]
  __shared__ float red[4][128];
  __shared__ float w2_lds[128];
  __shared__ float aq_lds[128];

  const int t = threadIdx.x, w = t >> 6, l = t & 63;
  const int blk = blockIdx.x;
  const int q = blk >> 8, k0 = (blk & 255)*128;

  // stage dist tile (issues 16 NT loads, 8 b128 LDS writes)
  stage_tile(dist + (size_t)q*NK_ + k0, QNK_, b_lds, w, l);

  // A-frags (W1-dist part) + BH frags while staging is in flight
  const bf16x8* wsa8 = (const bf16x8*)(ws + WSA_OFF);
  bf16x8 afr[8];
#pragma unroll
  for (int ks = 0; ks < 8; ks++) afr[ks] = wsa8[(32 + w*8 + ks)*64 + l];  // part 1
  const unsigned int* bh = (const unsigned int*)(ws + BH_OFF);
  u32x4 bhA[4], bhB[4];
#pragma unroll
  for (int ct = 0; ct < 4; ct++){
    const unsigned int* src = bh + (size_t)((((blk & 255)*4 + ct)*4 + w)*64 + l)*8;
    bhA[ct] = *(const u32x4*)src;
    bhB[ct] = *(const u32x4*)(src + 4);
  }
  if (t < 128) w2_lds[t] = W2[t];
  else         aq_lds[t - 128] = ws[AQ_OFF + q*128 + (t - 128)];
  __syncthreads();

  // per-lane W2/Aq row vectors (C/D rows: (r&3)+8*(r>>2)+4*(l>>5), + ot*32)
  const int hi4 = (l >> 5) << 2;
  float W2L[16], AqL[16];
#pragma unroll
  for (int r = 0; r < 16; r++){
    const int orow = w*32 + (r & 3) + 8*(r >> 2) + hi4;
    W2L[r] = w2_lds[orow];
    AqL[r] = aq_lds[orow];
  }

  const int nn = l & 31;
  const int cb2 = ((l >> 5) << 3)*2;
#pragma unroll
  for (int ct = 0; ct < 4; ct++){
    f32x16 acc;
#pragma unroll
    for (int j = 0; j < 4; j++){
      acc[2*j]   = bf_lo(bhA[ct][j]);  acc[2*j+1] = bf_hi(bhA[ct][j]);
      acc[8+2*j] = bf_lo(bhB[ct][j]);  acc[9+2*j] = bf_hi(bhB[ct][j]);
    }
    const int n = ct*32 + nn;
    const int swz = ((n >> 2) & 7) << 4;
#pragma unroll
    for (int ks = 0; ks < 8; ks++){
      const int byte = n*256 + ((ks*32 + cb2) ^ swz);     // FIXED: XOR full byte-in-row
      const bf16x8 bfr = *(const bf16x8*)((char*)b_lds + byte);
      acc = __builtin_amdgcn_mfma_f32_32x32x16_bf16(afr[ks], bfr, acc, 0, 0, 0);
    }
    float sl = 0.f;
#pragma unroll
    for (int r = 0; r < 16; r++)
      sl += W2L[r] * fmaxf(acc[r] + AqL[r], 0.f);
    sl += __shfl_xor(sl, 32, 64);
    if (l < 32) red[w][ct*32 + l] = sl;
  }
  __syncthreads();

  if (t < 128){
    const float s = b2p[0] + red[0][t] + red[1][t] + red[2][t] + red[3][t];
    __builtin_nontemporal_store(s, &scores[(size_t)q*NK_ + k0 + t]);
    float m = s;
#pragma unroll
    for (int off = 32; off > 0; off >>= 1) m = fminf(m, __shfl_xor(m, off, 64));
    if (l == 0) atomicMin((unsigned int*)(ws + MINKEY_OFF), fkey(m));
  }
}

// ---------------- softmax + PV partials ----------------
__global__ __launch_bounds__(256) void softmax_pv_kernel(
    const float* __restrict__ value, const int* __restrict__ mask,
    float* __restrict__ scores, float* __restrict__ ws)
{
  __shared__ float v_lds[128*128];    // XOR-swizzled [d][k]
  __shared__ __align__(16) float e_lds[8][128];
  __shared__ float wsum[8];
  const int t = threadIdx.x, bid = blockIdx.x, k0 = bid*128;
  const float floorv = fkey_dec(*(const unsigned int*)(ws + MINKEY_OFF)) - 20.0f;

  for (int i = t; i < 4096; i += 256){
    const int d = i >> 5, k4 = (i & 31)*4;
    const f32x4 v = __builtin_nontemporal_load((const f32x4*)&value[(size_t)d*NK_ + k0 + k4]);
    const int dw = (d*128 + k4) ^ ((d & 31) << 2);
    *(f32x4*)&v_lds[dw] = v;
  }

  {
    const int q = t >> 5, kk = (t & 31)*4;
    const size_t gi = (size_t)q*NK_ + k0 + kk;
    const f32x4 s4 = *(const f32x4*)&scores[gi];
    const i32x4 m4 = *(const i32x4*)&mask[gi];
    f32x4 sf, e;
#pragma unroll
    for (int j = 0; j < 4; j++){
      sf[j] = m4[j] ? s4[j] : s4[j] + floorv;
      e[j]  = __expf(sf[j]);
    }
    __builtin_nontemporal_store(sf, (f32x4*)&scores[gi]);   // final masked scores
    *(f32x4*)&e_lds[q][kk] = e;
    float es = e[0] + e[1] + e[2] + e[3];
#pragma unroll
    for (int off = 16; off > 0; off >>= 1) es += __shfl_xor(es, off, 64);
    if ((t & 31) == 0) wsum[q] = es;
  }
  __syncthreads();
  if (t < 8) ws[DENOM_OFF + t*NCH_ + bid] = wsum[t];

  const int d = t & 127, qb = (t >> 7)*4;
  f32x4 acc = {0.f,0.f,0.f,0.f};
#pragma unroll 8
  for (int k4 = 0; k4 < 128; k4 += 4){
    const int dw = (d*128 + k4) ^ ((d & 31) << 2);
    const f32x4 v  = *(const f32x4*)&v_lds[dw];
    const f32x4 e0 = *(const f32x4*)&e_lds[qb+0][k4];
    const f32x4 e1 = *(const f32x4*)&e_lds[qb+1][k4];
    const f32x4 e2 = *(const f32x4*)&e_lds[qb+2][k4];
    const f32x4 e3 = *(const f32x4*)&e_lds[qb+3][k4];
#pragma unroll
    for (int j = 0; j < 4; j++){
      acc[0] += v[j]*e0[j]; acc[1] += v[j]*e1[j];
      acc[2] += v[j]*e2[j]; acc[3] += v[j]*e3[j];
    }
  }
#pragma unroll
  for (int j = 0; j < 4; j++) ws[OUTV_OFF + (size_t)bid*1024 + d*8 + qb + j] = acc[j];
}

// ---------------- finalize: 32 blocks, coalesced chunk reduce ----------------
__global__ __launch_bounds__(256) void finalize_kernel(const float* __restrict__ ws,
    float* __restrict__ out){
  __shared__ float dsum[8];
  __shared__ float red[8][32];
  const int t = threadIdx.x, bid = blockIdx.x;

  if (t < 64){
    const int q = t >> 3, i = t & 7;
    float s = 0.f;
    for (int j = 0; j < 32; j++) s += ws[DENOM_OFF + q*NCH_ + i + 8*j];
#pragma unroll
    for (int off = 4; off > 0; off >>= 1) s += __shfl_xor(s, off, 64);
    if (i == 0) dsum[q] = s;
  }

  const int ol = t & 31, part = t >> 5;
  float s = 0.f;
  for (int j = 0; j < 32; j++)
    s += ws[OUTV_OFF + (size_t)(part + 8*j)*1024 + bid*32 + ol];
  red[part][ol] = s;
  __syncthreads();

  if (t < 32){
    float a = 0.f;
#pragma unroll
    for (int p = 0; p < 8; p++) a += red[p][t];
    const int o = bid*32 + t;
    out[o] = a / dsum[o & 7];
  }
}

extern "C" void kernel_launch(void* const* d_in, const int* in_sizes, int n_in,
                              void* d_out, int out_size, void* d_ws, size_t ws_size,
                              hipStream_t stream){
  const float* query=(const float*)d_in[0];
  const float* keys =(const float*)d_in[1];
  const float* value=(const float*)d_in[2];
  const float* dist =(const float*)d_in[3];
  const int*   mask =(const int*)d_in[4];
  const float* W1   =(const float*)d_in[5];
  const float* b1   =(const float*)d_in[6];
  const float* W2   =(const float*)d_in[7];
  const float* b2   =(const float*)d_in[8];
  float* out=(float*)d_out;
  float* scores=out+1024;
  float* ws=(float*)d_ws;

  prep_kernel      <<<17,256,0,stream>>>(query,W1,b1,ws);
  bkprep_kernel    <<<256,256,0,stream>>>(keys,ws);
  scores_kernel    <<<2048,256,0,stream>>>(dist,W2,b2,ws,scores);
  softmax_pv_kernel<<<NCH_,256,0,stream>>>(value,mask,scores,ws);
  finalize_kernel  <<<32,256,0,stream>>>(ws,out);
}

// Round 9
// 97.622 us; speedup vs baseline: 1.0008x; 1.0008x over previous
//
#include <hip/hip_runtime.h>
#include <hip/hip_bf16.h>
#include <math.h>

#define C_    128
#define NQ_   8
#define NK_   32768
#define QNK_  (NQ_*NK_)
#define NCH_  256         // softmax chunks of 128 cols

// ws float offsets
#define AQ_OFF     0        // [q][o] 1024
#define MINKEY_OFF 1024     // 1 uint (order-preserving float key)
#define DENOM_OFF  1040     // 8*256
#define OUTV_OFF   4096     // 256*1024 -> 266240
#define WSA_OFF    266240   // A-frag table: 64 frags x 64 lanes x 8 bf16 = 16384 u32
#define BH_OFF     282624   // Bk frag table: 256 kt x 4 ct x 4 w x 64 lanes x 8 u32 = 2M u32

typedef float f32x4  __attribute__((ext_vector_type(4)));
typedef float f32x16 __attribute__((ext_vector_type(16)));
typedef int   i32x4  __attribute__((ext_vector_type(4)));
typedef short bf16x8 __attribute__((ext_vector_type(8)));
typedef unsigned int u32x4 __attribute__((ext_vector_type(4)));

__device__ inline unsigned short f2bf(float f){ // prep only
  unsigned u = __float_as_uint(f);
  return (unsigned short)((u + 0x7FFFu + ((u >> 16) & 1u)) >> 16);
}
__device__ inline unsigned int pkbf(float a, float b){
  __hip_bfloat162 h = __float22bfloat162_rn(make_float2(a, b)); // v_cvt_pk_bf16_f32
  union { __hip_bfloat162 h2; unsigned int u; } cv; cv.h2 = h; return cv.u;
}
__device__ inline float bf_lo(unsigned u){ return __uint_as_float(u << 16); }
__device__ inline float bf_hi(unsigned u){ return __uint_as_float(u & 0xFFFF0000u); }
__device__ inline unsigned int fkey(float f){
  unsigned u = __float_as_uint(f);
  return (u & 0x80000000u) ? ~u : (u | 0x80000000u);
}
__device__ inline float fkey_dec(unsigned key){
  unsigned u = (key & 0x80000000u) ? (key & 0x7FFFFFFFu) : ~key;
  return __uint_as_float(u);
}

// ---------------- prep0: A-frag table (32x32x16 layout) + Aq + minkey init ----
// frag f = part*32 + ot*8 + ks; element [f][l][e] =
//   W1[ (ot*32 + (l&31))*384 + 128 + part*128 + ks*16 + (l>>5)*8 + e ]
__global__ __launch_bounds__(256) void prep_kernel(const float* __restrict__ query,
    const float* __restrict__ W1, const float* __restrict__ b1, float* __restrict__ ws){
  const int t = threadIdx.x, b = blockIdx.x;
  if (b < 16){
    unsigned int* wsa = (unsigned int*)(ws + WSA_OFF);
    for (int u = b*1024 + t; u < (b+1)*1024; u += 256){
      unsigned int pack = 0;
#pragma unroll
      for (int e2 = 0; e2 < 2; e2++){
        const int E = u*2 + e2;
        const int f = E >> 9, l = (E >> 3) & 63, e = E & 7;
        const int part = f >> 5, ot = (f >> 3) & 3, ks = f & 7;
        const int o = ot*32 + (l & 31);
        const int c = ks*16 + ((l >> 5) << 3) + e;
        pack |= (unsigned int)f2bf(W1[o*384 + 128 + part*128 + c]) << (16*e2);
      }
      wsa[u] = pack;
    }
  } else {
    if (t == 0) *(unsigned int*)(ws + MINKEY_OFF) = 0xFFFFFFFFu;
    const int o = t >> 1, h = t & 1;
    float s[8];
#pragma unroll
    for (int q = 0; q < 8; q++) s[q] = 0.f;
    for (int c = h*64; c < h*64 + 64; c++){
      const float wv = W1[o*384 + c];
#pragma unroll
      for (int q = 0; q < 8; q++) s[q] += wv * query[c*8 + q];
    }
#pragma unroll
    for (int q = 0; q < 8; q++){
      s[q] += __shfl_xor(s[q], 1, 64);
      if (h == 0) ws[AQ_OFF + q*128 + o] = s[q] + b1[o];
    }
  }
}

// ---- shared staging: fp32 [c][n]-global -> swizzled bf16 LDS [n 128][c 128] ----
// thread: h = 2w + (l>>5) (c-octet), n4 = (l&31)*4. b128 LDS writes.
// element (n, c): byte = n*256 + ( (c*2 within row) ^ (((n>>2)&7)<<4) )
__device__ inline void stage_tile(const float* __restrict__ src, size_t stride,
                                  unsigned short* __restrict__ lds, int w, int l){
  const int h  = 2*w + (l >> 5);
  const int n4 = (l & 31)*4;
  const float* base = src + (size_t)(h*8)*stride + n4;
#pragma unroll
  for (int p = 0; p < 2; p++){
    f32x4 v[8];
#pragma unroll
    for (int s = 0; s < 8; s++)
      v[s] = __builtin_nontemporal_load((const f32x4*)(base + (size_t)(64*p + s)*stride));
#pragma unroll
    for (int j = 0; j < 4; j++){
      const int n = n4 + j;
      u32x4 pk;
      pk[0] = pkbf(v[0][j], v[1][j]);
      pk[1] = pkbf(v[2][j], v[3][j]);
      pk[2] = pkbf(v[4][j], v[5][j]);
      pk[3] = pkbf(v[6][j], v[7][j]);
      const int byte = n*256 + ((h*16 + p*128) ^ (((n >> 2) & 7) << 4));
      *(u32x4*)((char*)lds + byte) = pk;
    }
  }
}

// ---------------- bkprep: BH[kt][ct][w][lane][16] = C-frags of W1k x keys -----
__global__ __launch_bounds__(256) void bkprep_kernel(const float* __restrict__ keys,
    float* __restrict__ ws){
  __shared__ unsigned short b_lds[128*128]; // 128n x 128c bf16 = 32KB
  const int t = threadIdx.x, w = t >> 6, l = t & 63;
  const int blk = blockIdx.x, k0 = blk*128;

  const bf16x8* wsa8 = (const bf16x8*)(ws + WSA_OFF);
  bf16x8 afr[8];
#pragma unroll
  for (int ks = 0; ks < 8; ks++) afr[ks] = wsa8[(w*8 + ks)*64 + l];   // part 0

  stage_tile(keys + k0, NK_, b_lds, w, l);
  __syncthreads();

  unsigned int* bh = (unsigned int*)(ws + BH_OFF);
  const int nn = l & 31;
  const int cb2 = ((l >> 5) << 3)*2;   // byte offset of this lane's c-octet
#pragma unroll
  for (int ct = 0; ct < 4; ct++){
    f32x16 acc = {};
    const int n = ct*32 + nn;
    const int swz = ((n >> 2) & 7) << 4;
#pragma unroll
    for (int ks = 0; ks < 8; ks++){
      const int byte = n*256 + ((ks*32 + cb2) ^ swz);
      const bf16x8 bfr = *(const bf16x8*)((char*)b_lds + byte);
      acc = __builtin_amdgcn_mfma_f32_32x32x16_bf16(afr[ks], bfr, acc, 0, 0, 0);
    }
    u32x4 pA, pB;
#pragma unroll
    for (int j = 0; j < 4; j++){ pA[j] = pkbf(acc[2*j], acc[2*j+1]);
                                 pB[j] = pkbf(acc[8+2*j], acc[9+2*j]); }
    unsigned int* dst = bh + (size_t)(((blk*4 + ct)*4 + w)*64 + l)*8;
    *(u32x4*)dst = pA;
    *(u32x4*)(dst + 4) = pB;
  }
}

// ---------------- scores: one-shot 128-col blocks, 32x32x16 MFMA --------------
// Register diet vs round 8: no W2L/AqL arrays (epilogue reads LDS),
// __launch_bounds__(256,3) caps VGPR ~170 so the ct streams serialize, not spill.
__global__ __launch_bounds__(256, 3) void scores_kernel(
    const float* __restrict__ dist, const float* __restrict__ W2,
    const float* __restrict__ b2p, float* __restrict__ ws,
    float* __restrict__ scores)
{
  __shared__ unsigned short b_lds[128*128];   // 32KB swizzled [n][c]
  __shared__ float red[4][128];
  __shared__ float w2_lds[128];
  __shared__ float aq_lds[128];

  const int t = threadIdx.x, w = t >> 6, l = t & 63;
  const int blk = blockIdx.x;
  const int q = blk >> 8, k0 = (blk & 255)*128;

  // stage dist tile (issues 16 NT loads, 8 b128 LDS writes)
  stage_tile(dist + (size_t)q*NK_ + k0, QNK_, b_lds, w, l);

  // A-frags (W1-dist part) + BH frags while staging is in flight
  const bf16x8* wsa8 = (const bf16x8*)(ws + WSA_OFF);
  bf16x8 afr[8];
#pragma unroll
  for (int ks = 0; ks < 8; ks++) afr[ks] = wsa8[(32 + w*8 + ks)*64 + l];  // part 1
  const unsigned int* bh = (const unsigned int*)(ws + BH_OFF);
  u32x4 bhA[4], bhB[4];
#pragma unroll
  for (int ct = 0; ct < 4; ct++){
    const unsigned int* src = bh + (size_t)((((blk & 255)*4 + ct)*4 + w)*64 + l)*8;
    bhA[ct] = *(const u32x4*)src;
    bhB[ct] = *(const u32x4*)(src + 4);
  }
  if (t < 128) w2_lds[t] = W2[t];
  else         aq_lds[t - 128] = ws[AQ_OFF + q*128 + (t - 128)];
  __syncthreads();

  const int nn = l & 31;
  const int cb2 = ((l >> 5) << 3)*2;
  const int hi4 = (l >> 5) << 2;
#pragma unroll
  for (int ct = 0; ct < 4; ct++){
    f32x16 acc;
#pragma unroll
    for (int j = 0; j < 4; j++){
      acc[2*j]   = bf_lo(bhA[ct][j]);  acc[2*j+1] = bf_hi(bhA[ct][j]);
      acc[8+2*j] = bf_lo(bhB[ct][j]);  acc[9+2*j] = bf_hi(bhB[ct][j]);
    }
    const int n = ct*32 + nn;
    const int swz = ((n >> 2) & 7) << 4;
#pragma unroll
    for (int ks = 0; ks < 8; ks++){
      const int byte = n*256 + ((ks*32 + cb2) ^ swz);
      const bf16x8 bfr = *(const bf16x8*)((char*)b_lds + byte);
      acc = __builtin_amdgcn_mfma_f32_32x32x16_bf16(afr[ks], bfr, acc, 0, 0, 0);
    }
    // epilogue: read W2/Aq straight from LDS (no register arrays)
    float sl = 0.f;
#pragma unroll
    for (int r = 0; r < 16; r++){
      const int orow = w*32 + (r & 3) + 8*(r >> 2) + hi4;
      sl += w2_lds[orow] * fmaxf(acc[r] + aq_lds[orow], 0.f);
    }
    sl += __shfl_xor(sl, 32, 64);
    if (l < 32) red[w][ct*32 + l] = sl;
  }
  __syncthreads();

  if (t < 128){
    const float s = b2p[0] + red[0][t] + red[1][t] + red[2][t] + red[3][t];
    __builtin_nontemporal_store(s, &scores[(size_t)q*NK_ + k0 + t]);
    float m = s;
#pragma unroll
    for (int off = 32; off > 0; off >>= 1) m = fminf(m, __shfl_xor(m, off, 64));
    if (l == 0) atomicMin((unsigned int*)(ws + MINKEY_OFF), fkey(m));
  }
}

// ---------------- softmax + PV partials ----------------
__global__ __launch_bounds__(256) void softmax_pv_kernel(
    const float* __restrict__ value, const int* __restrict__ mask,
    float* __restrict__ scores, float* __restrict__ ws)
{
  __shared__ float v_lds[128*128];    // XOR-swizzled [d][k]
  __shared__ __align__(16) float e_lds[8][128];
  __shared__ float wsum[8];
  const int t = threadIdx.x, bid = blockIdx.x, k0 = bid*128;
  const float floorv = fkey_dec(*(const unsigned int*)(ws + MINKEY_OFF)) - 20.0f;

  for (int i = t; i < 4096; i += 256){
    const int d = i >> 5, k4 = (i & 31)*4;
    const f32x4 v = __builtin_nontemporal_load((const f32x4*)&value[(size_t)d*NK_ + k0 + k4]);
    const int dw = (d*128 + k4) ^ ((d & 31) << 2);
    *(f32x4*)&v_lds[dw] = v;
  }

  {
    const int q = t >> 5, kk = (t & 31)*4;
    const size_t gi = (size_t)q*NK_ + k0 + kk;
    const f32x4 s4 = *(const f32x4*)&scores[gi];
    const i32x4 m4 = *(const i32x4*)&mask[gi];
    f32x4 sf, e;
#pragma unroll
    for (int j = 0; j < 4; j++){
      sf[j] = m4[j] ? s4[j] : s4[j] + floorv;
      e[j]  = __expf(sf[j]);
    }
    __builtin_nontemporal_store(sf, (f32x4*)&scores[gi]);   // final masked scores
    *(f32x4*)&e_lds[q][kk] = e;
    float es = e[0] + e[1] + e[2] + e[3];
#pragma unroll
    for (int off = 16; off > 0; off >>= 1) es += __shfl_xor(es, off, 64);
    if ((t & 31) == 0) wsum[q] = es;
  }
  __syncthreads();
  if (t < 8) ws[DENOM_OFF + t*NCH_ + bid] = wsum[t];

  const int d = t & 127, qb = (t >> 7)*4;
  f32x4 acc = {0.f,0.f,0.f,0.f};
#pragma unroll 8
  for (int k4 = 0; k4 < 128; k4 += 4){
    const int dw = (d*128 + k4) ^ ((d & 31) << 2);
    const f32x4 v  = *(const f32x4*)&v_lds[dw];
    const f32x4 e0 = *(const f32x4*)&e_lds[qb+0][k4];
    const f32x4 e1 = *(const f32x4*)&e_lds[qb+1][k4];
    const f32x4 e2 = *(const f32x4*)&e_lds[qb+2][k4];
    const f32x4 e3 = *(const f32x4*)&e_lds[qb+3][k4];
#pragma unroll
    for (int j = 0; j < 4; j++){
      acc[0] += v[j]*e0[j]; acc[1] += v[j]*e1[j];
      acc[2] += v[j]*e2[j]; acc[3] += v[j]*e3[j];
    }
  }
#pragma unroll
  for (int j = 0; j < 4; j++) ws[OUTV_OFF + (size_t)bid*1024 + d*8 + qb + j] = acc[j];
}

// ---------------- finalize: 32 blocks, coalesced chunk reduce ----------------
__global__ __launch_bounds__(256) void finalize_kernel(const float* __restrict__ ws,
    float* __restrict__ out){
  __shared__ float dsum[8];
  __shared__ float red[8][32];
  const int t = threadIdx.x, bid = blockIdx.x;

  if (t < 64){
    const int q = t >> 3, i = t & 7;
    float s = 0.f;
    for (int j = 0; j < 32; j++) s += ws[DENOM_OFF + q*NCH_ + i + 8*j];
#pragma unroll
    for (int off = 4; off > 0; off >>= 1) s += __shfl_xor(s, off, 64);
    if (i == 0) dsum[q] = s;
  }

  const int ol = t & 31, part = t >> 5;
  float s = 0.f;
  for (int j = 0; j < 32; j++)
    s += ws[OUTV_OFF + (size_t)(part + 8*j)*1024 + bid*32 + ol];
  red[part][ol] = s;
  __syncthreads();

  if (t < 32){
    float a = 0.f;
#pragma unroll
    for (int p = 0; p < 8; p++) a += red[p][t];
    const int o = bid*32 + t;
    out[o] = a / dsum[o & 7];
  }
}

extern "C" void kernel_launch(void* const* d_in, const int* in_sizes, int n_in,
                              void* d_out, int out_size, void* d_ws, size_t ws_size,
                              hipStream_t stream){
  const float* query=(const float*)d_in[0];
  const float* keys =(const float*)d_in[1];
  const float* value=(const float*)d_in[2];
  const float* dist =(const float*)d_in[3];
  const int*   mask =(const int*)d_in[4];
  const float* W1   =(const float*)d_in[5];
  const float* b1   =(const float*)d_in[6];
  const float* W2   =(const float*)d_in[7];
  const float* b2   =(const float*)d_in[8];
  float* out=(float*)d_out;
  float* scores=out+1024;
  float* ws=(float*)d_ws;

  prep_kernel      <<<17,256,0,stream>>>(query,W1,b1,ws);
  bkprep_kernel    <<<256,256,0,stream>>>(keys,ws);
  scores_kernel    <<<2048,256,0,stream>>>(dist,W2,b2,ws,scores);
  softmax_pv_kernel<<<NCH_,256,0,stream>>>(value,mask,scores,ws);
  finalize_kernel  <<<32,256,0,stream>>>(ws,out);
}